// Round 1
// baseline (286.390 us; speedup 1.0000x reference)
//
#include <hip/hip_runtime.h>

// Factored attention: only the t=T-1 query row matters (reference returns
// out[:, -1, :]). K/V projections are algebraically eliminated:
//   score[s] = (xs_s . u + q.bk)/16,  u = Wk^T q           (q unmasked)
//   score[s] = NEG * S_q / 16                               (s masked)
//   score[s] = NEG * (xs_s . c + sum(bk)) / 16, c=colsum(Wk) (q masked)
//   score[s] = 256*NEG^2/16 = 1.6e11                         (both masked)
//   out = (sum_s p_s xs_s) @ Wv^T + bv
// 6250x-amplified score paths computed in fp64; smooth paths fp32.

namespace {
constexpr int kB = 2048;
constexpr int kT = 50;
constexpr int kD = 256;
constexpr int kG = 8;      // batches per workgroup
constexpr int kThr = 512;  // 8 waves
constexpr int kCH = 25;    // rows per online-softmax chunk (2 chunks of 25)
constexpr double kNeg = -100000.0;
}  // namespace

__global__ void precompute_c(const float* __restrict__ Wk,
                             const float* __restrict__ bk,
                             double* __restrict__ ws) {
  const int d = threadIdx.x;  // 256 threads
  double c = 0.0;
  for (int e = 0; e < kD; ++e) c += (double)Wk[(size_t)e * kD + d];
  ws[d] = c;
  if (d == 0) {
    double s = 0.0;
    for (int e = 0; e < kD; ++e) s += (double)bk[e];
    ws[kD] = s;
  }
}

__global__ __launch_bounds__(kThr) void attn_fused(
    const float* __restrict__ x, const int* __restrict__ mask,
    const float* __restrict__ td, const float* __restrict__ Wq,
    const float* __restrict__ bq, const float* __restrict__ Wk,
    const float* __restrict__ bk, const float* __restrict__ Wv,
    const float* __restrict__ bv, const double* __restrict__ cws,
    float* __restrict__ out) {
  __shared__ __align__(16) float chunkbuf[kCH][kD];  // 25.6 KB
  __shared__ __align__(16) float xs49[kG][kD];       // 8 KB
  __shared__ __align__(16) float qf[kG][kD];         // 8 KB
  __shared__ __align__(16) float ub[kG][kD];         // 8 KB
  __shared__ __align__(16) float yb[kG][kD];         // 8 KB
  __shared__ double scb[kCH];
  __shared__ float pb[kCH];
  __shared__ double Sq[kG], Qbk[kG];
  __shared__ double msh, lsh, ash;
  __shared__ int mq[kG];

  const int t = threadIdx.x;
  const int wave = t >> 6;
  const int lane = t & 63;
  const int b0 = blockIdx.x * kG;

  // ---- meta + last-row staging ----
  if (t < kG) mq[t] = mask[(b0 + t) * kT + (kT - 1)];
  for (int idx = t; idx < kG * kD; idx += kThr) {
    const int g = idx >> 8, d = idx & (kD - 1);
    const int b = b0 + g;
    xs49[g][d] =
        x[((size_t)b * kT + (kT - 1)) * kD + d] * td[b * kT + (kT - 1)];
  }
  __syncthreads();

  // ---- B1: q_g = Wq @ xs49_g + bq (each thread: one e, 4 batches) ----
  {
    const int e = t & (kD - 1);
    const int gh = t >> 8;  // 0 or 1 -> g = gh*4 + j
    float acc[4] = {0.f, 0.f, 0.f, 0.f};
    const float4* wr = (const float4*)(Wq + (size_t)e * kD);
    for (int i = 0; i < kD / 4; ++i) {
      const float4 w = wr[i];
#pragma unroll
      for (int j = 0; j < 4; ++j) {
        const float4 a = ((const float4*)(&xs49[gh * 4 + j][0]))[i];
        acc[j] += w.x * a.x + w.y * a.y + w.z * a.z + w.w * a.w;
      }
    }
#pragma unroll
    for (int j = 0; j < 4; ++j) qf[gh * 4 + j][e] = acc[j] + bq[e];
  }
  __syncthreads();

  // ---- S_q and q.bk per batch (wave w handles g = w), fp64 ----
  {
    const int g = wave;
    double s = 0.0, s2 = 0.0;
#pragma unroll
    for (int i = 0; i < 4; ++i) {
      const int e = lane + 64 * i;
      const double q = (double)qf[g][e];
      s += q;
      s2 += q * (double)bk[e];
    }
#pragma unroll
    for (int off = 32; off; off >>= 1) {
      s += __shfl_down(s, off);
      s2 += __shfl_down(s2, off);
    }
    if (lane == 0) {
      Sq[g] = s;
      Qbk[g] = s2;
    }
  }

  // ---- B2: u_g[d] = sum_e Wk[e][d] * q_g[e] (coalesced Wk stream) ----
  {
    const int d = t & (kD - 1);
    const int gh = t >> 8;
    float acc[4] = {0.f, 0.f, 0.f, 0.f};
    for (int e = 0; e < kD; ++e) {
      const float w = Wk[(size_t)e * kD + d];
#pragma unroll
      for (int j = 0; j < 4; ++j) acc[j] += w * qf[gh * 4 + j][e];
    }
#pragma unroll
    for (int j = 0; j < 4; ++j) ub[gh * 4 + j][d] = acc[j];
  }
  __syncthreads();

  const double sbk = cws[kD];

  // ---- per-batch attention with chunked online softmax ----
  for (int g = 0; g < kG; ++g) {
    const int b = b0 + g;
    const int mqg = mq[g];
    float y = 0.f;  // valid for t < kD

    __syncthreads();
    if (t == 0) {
      msh = -1.0e300;
      lsh = 0.0;
      ash = 0.0;
    }
    __syncthreads();

    for (int c = 0; c < kT / kCH; ++c) {
      const int s0 = c * kCH;
      // stage chunk rows, scaled by time_decay
      for (int i4 = t; i4 < kCH * kD / 4; i4 += kThr) {
        const int sl = i4 >> 6;           // local row
        const int col4 = i4 & 63;         // float4 column
        const int sg = s0 + sl;           // global row
        const float tv = td[b * kT + sg];
        float4 xv =
            ((const float4*)(x + ((size_t)b * kT + sg) * kD))[col4];
        xv.x *= tv;
        xv.y *= tv;
        xv.z *= tv;
        xv.w *= tv;
        ((float4*)(&chunkbuf[sl][0]))[col4] = xv;
      }
      __syncthreads();

      // scores for the chunk: wave w -> local s = w, w+8, ...
      for (int sl = wave; sl < kCH; sl += kThr / 64) {
        double dot = 0.0;
        if (mqg != 0) {
#pragma unroll
          for (int i = 0; i < 4; ++i) {
            const int d = lane + 64 * i;
            dot += (double)chunkbuf[sl][d] * (double)ub[g][d];
          }
        } else {
#pragma unroll
          for (int i = 0; i < 4; ++i) {
            const int d = lane + 64 * i;
            dot += (double)chunkbuf[sl][d] * cws[d];
          }
        }
#pragma unroll
        for (int off = 32; off; off >>= 1) dot += __shfl_down(dot, off);
        if (lane == 0) {
          const int ms = mask[b * kT + (s0 + sl)];
          double sc;
          if (mqg != 0)
            sc = ms ? (dot + Qbk[g]) * 0.0625 : kNeg * Sq[g] * 0.0625;
          else
            sc = ms ? kNeg * (dot + sbk) * 0.0625 : 256.0 * 1.0e10 * 0.0625;
          scb[sl] = sc;
        }
      }
      __syncthreads();

      // online-softmax update (wave 0)
      if (wave == 0) {
        const double v = (lane < kCH) ? scb[lane] : -1.0e300;
        double mc = v;
#pragma unroll
        for (int off = 32; off; off >>= 1) {
          const double o = __shfl_xor(mc, off);
          mc = mc > o ? mc : o;
        }
        const double mold = msh;
        const double mnew = mc > mold ? mc : mold;
        const double a = exp(mold - mnew);
        const double p = (lane < kCH) ? exp(v - mnew) : 0.0;
        double sump = p;
#pragma unroll
        for (int off = 32; off; off >>= 1) sump += __shfl_xor(sump, off);
        if (lane < kCH) pb[lane] = (float)p;
        if (lane == 0) {
          lsh = lsh * a + sump;
          msh = mnew;
          ash = a;
        }
      }
      __syncthreads();

      // y update (threads 0..255 own one d each)
      if (t < kD) {
        const float a = (float)ash;
        float acc = 0.f;
        for (int sl = 0; sl < kCH; ++sl) acc += pb[sl] * chunkbuf[sl][t];
        y = y * a + acc;
      }
      __syncthreads();  // protect chunkbuf/pb/scb before next chunk
    }

    if (t < kD) yb[g][t] = (float)((double)y / lsh);
  }
  __syncthreads();

  // ---- D: out_g = Wv @ y_g + bv ----
  {
    const int e = t & (kD - 1);
    const int gh = t >> 8;
    float acc[4] = {0.f, 0.f, 0.f, 0.f};
    const float4* wr = (const float4*)(Wv + (size_t)e * kD);
    for (int i = 0; i < kD / 4; ++i) {
      const float4 w = wr[i];
#pragma unroll
      for (int j = 0; j < 4; ++j) {
        const float4 yv = ((const float4*)(&yb[gh * 4 + j][0]))[i];
        acc[j] += w.x * yv.x + w.y * yv.y + w.z * yv.z + w.w * yv.w;
      }
    }
#pragma unroll
    for (int j = 0; j < 4; ++j)
      out[(size_t)(b0 + gh * 4 + j) * kD + e] = acc[j] + bv[e];
  }
}

extern "C" void kernel_launch(void* const* d_in, const int* in_sizes, int n_in,
                              void* d_out, int out_size, void* d_ws,
                              size_t ws_size, hipStream_t stream) {
  const float* x = (const float*)d_in[0];
  const int* mask = (const int*)d_in[1];
  const float* td = (const float*)d_in[2];
  const float* Wq = (const float*)d_in[3];
  const float* bq = (const float*)d_in[4];
  const float* Wk = (const float*)d_in[5];
  const float* bk = (const float*)d_in[6];
  const float* Wv = (const float*)d_in[7];
  const float* bv = (const float*)d_in[8];
  double* ws = (double*)d_ws;  // needs 257 doubles; ws_size is far larger
  float* out = (float*)d_out;

  hipLaunchKernelGGL(precompute_c, dim3(1), dim3(kD), 0, stream, Wk, bk, ws);
  hipLaunchKernelGGL(attn_fused, dim3(kB / kG), dim3(kThr), 0, stream, x, mask,
                     td, Wq, bq, Wk, bk, Wv, bv, (const double*)ws, out);
}

// Round 2
// 220.877 us; speedup vs baseline: 1.2966x; 1.2966x over previous
//
#include <hip/hip_runtime.h>

// Factored single-row attention (reference returns out[:, -1, :] only).
//   q = Wq xs49 + bq ; u = Wk^T q ; c = colsum(Wk) (folded into B2)
//   score[s]: q-kept & s-kept : (xs_s.u + q.bk)/16
//             q-kept & s-masked: NEG*sum(q)/16            (const per batch)
//             q-masked & s-kept: NEG*(xs_s.c + sum(bk))/16
//             both masked      : 256*NEG^2/16 = 1.6e11     (const)
//   out = Wv (sum_s p_s xs_s) + bv
// block=256thr/4 waves, G=4 batches, grid=512. Cooperative matvecs (B1/B2/D);
// attention middle: ONE WAVE PER BATCH, zero barriers — lane l owns columns
// 4l..4l+3, coalesced dwordx4 row stream with 2-row unroll+prefetch,
// shfl_xor reduce, online softmax (fp64 score bookkeeping, fp32 expf of
// fp64-accurate differences), y accumulated in registers.

namespace {
constexpr int kB = 2048;
constexpr int kT = 50;
constexpr int kD = 256;
constexpr int kG = 4;      // batches per workgroup == waves per block
constexpr int kThr = 256;  // 4 waves
constexpr double kNeg = -100000.0;
}  // namespace

__global__ __launch_bounds__(kThr) void attn_fused(
    const float* __restrict__ x, const int* __restrict__ mask,
    const float* __restrict__ td, const float* __restrict__ Wq,
    const float* __restrict__ bq, const float* __restrict__ Wk,
    const float* __restrict__ bk, const float* __restrict__ Wv,
    const float* __restrict__ bv, float* __restrict__ out) {
  __shared__ __align__(16) float xs49[kG][kD];  // 4 KB
  __shared__ __align__(16) float qf[kG][kD];    // 4 KB
  __shared__ __align__(16) float ub[kG][kD];    // 4 KB
  __shared__ __align__(16) float yb[kG][kD];    // 4 KB
  __shared__ __align__(16) float cb[kD];        // 1 KB
  __shared__ float tdb[kG * kT];
  __shared__ int mb[kG * kT];
  __shared__ double Sqb[kG], Qbkb[kG], sbkb;

  const int t = threadIdx.x;
  const int wave = t >> 6;
  const int lane = t & 63;
  const int b0 = blockIdx.x * kG;

  // ---- stage td/mask (contiguous 200 each) and xs49 ----
  if (t < kG * kT) {
    tdb[t] = td[b0 * kT + t];
    mb[t] = mask[b0 * kT + t];
  }
  {
    const int g = t >> 6;   // batch 0..3
    const int c4 = t & 63;  // float4 column
    const float tv = td[(b0 + g) * kT + (kT - 1)];
    float4 xv =
        ((const float4*)(x + ((size_t)(b0 + g) * kT + kT - 1) * kD))[c4];
    xv.x *= tv; xv.y *= tv; xv.z *= tv; xv.w *= tv;
    ((float4*)(&xs49[g][0]))[c4] = xv;
  }
  __syncthreads();

  // ---- B1: q_j[e] = Wq[e,:] . xs49_j + bq[e] (thread t owns e=t) ----
  {
    const int e = t;
    float acc[kG] = {0.f, 0.f, 0.f, 0.f};
    const float4* wr = (const float4*)(Wq + (size_t)e * kD);
    for (int i = 0; i < kD / 4; ++i) {
      const float4 w = wr[i];
#pragma unroll
      for (int j = 0; j < kG; ++j) {
        const float4 a = ((const float4*)(&xs49[j][0]))[i];
        acc[j] += w.x * a.x + w.y * a.y + w.z * a.z + w.w * a.w;
      }
    }
    const float be = bq[e];
#pragma unroll
    for (int j = 0; j < kG; ++j) qf[j][e] = acc[j] + be;
  }
  __syncthreads();

  // ---- per-batch scalars: S_q, q.bk (wave g -> batch g); sbk (wave 0) ----
  {
    const int g = wave;
    double s = 0.0, s2 = 0.0, s3 = 0.0;
#pragma unroll
    for (int i = 0; i < 4; ++i) {
      const int e = lane + 64 * i;
      const double q = (double)qf[g][e];
      const double bke = (double)bk[e];
      s += q;
      s2 += q * bke;
      s3 += bke;
    }
#pragma unroll
    for (int off = 32; off; off >>= 1) {
      s += __shfl_xor(s, off);
      s2 += __shfl_xor(s2, off);
      s3 += __shfl_xor(s3, off);
    }
    if (lane == 0) {
      Sqb[g] = s;
      Qbkb[g] = s2;
      if (g == 0) sbkb = s3;
    }
  }

  // ---- B2: u_j[d] = sum_e Wk[e][d] q_j[e]; c[d] = sum_e Wk[e][d] ----
  {
    const int d = t;
    float uacc[kG] = {0.f, 0.f, 0.f, 0.f};
    double cacc = 0.0;
    for (int e4 = 0; e4 < kD / 4; ++e4) {
      const float w0 = Wk[(size_t)(4 * e4 + 0) * kD + d];
      const float w1 = Wk[(size_t)(4 * e4 + 1) * kD + d];
      const float w2 = Wk[(size_t)(4 * e4 + 2) * kD + d];
      const float w3 = Wk[(size_t)(4 * e4 + 3) * kD + d];
#pragma unroll
      for (int j = 0; j < kG; ++j) {
        const float4 q4 = ((const float4*)(&qf[j][0]))[e4];
        uacc[j] += w0 * q4.x + w1 * q4.y + w2 * q4.z + w3 * q4.w;
      }
      cacc += (double)w0 + (double)w1 + (double)w2 + (double)w3;
    }
#pragma unroll
    for (int j = 0; j < kG; ++j) ub[j][d] = uacc[j];
    cb[d] = (float)cacc;
  }
  __syncthreads();

  // ---- attention: wave g streams batch b0+g, zero barriers ----
  {
    const int g = wave;
    const int b = b0 + g;
    const float4* xrow = (const float4*)(x + (size_t)b * kT * kD);
    const float4 u4 = ((const float4*)(&ub[g][0]))[lane];
    const float4 c4 = ((const float4*)(&cb[0]))[lane];
    const int mqg = mb[g * kT + (kT - 1)];
    float4 v4;
    v4.x = mqg ? u4.x : c4.x;
    v4.y = mqg ? u4.y : c4.y;
    v4.z = mqg ? u4.z : c4.z;
    v4.w = mqg ? u4.w : c4.w;
    const double Cm = kNeg * Sqb[g] * 0.0625;    // q kept, s masked
    const double Cbb = 256.0 * 1.0e10 * 0.0625;  // both masked
    const double Qbk = Qbkb[g];
    const double sbk = sbkb;

    double m = -1.0e300;
    float l = 0.f;
    float4 y = {0.f, 0.f, 0.f, 0.f};

    float4 n0 = xrow[0 * 64 + lane];
    float4 n1 = xrow[1 * 64 + lane];
    for (int s = 0; s < kT; s += 2) {
      const float4 r0 = n0, r1 = n1;
      if (s + 2 < kT) n0 = xrow[(s + 2) * 64 + lane];
      if (s + 3 < kT) n1 = xrow[(s + 3) * 64 + lane];
      const float tv0 = tdb[g * kT + s];
      const float tv1 = tdb[g * kT + s + 1];
      float4 a0, a1;
      a0.x = r0.x * tv0; a0.y = r0.y * tv0;
      a0.z = r0.z * tv0; a0.w = r0.w * tv0;
      a1.x = r1.x * tv1; a1.y = r1.y * tv1;
      a1.z = r1.z * tv1; a1.w = r1.w * tv1;
      float p0 = a0.x * v4.x + a0.y * v4.y + a0.z * v4.z + a0.w * v4.w;
      float p1 = a1.x * v4.x + a1.y * v4.y + a1.z * v4.z + a1.w * v4.w;
#pragma unroll
      for (int off = 32; off; off >>= 1) {
        p0 += __shfl_xor(p0, off);
        p1 += __shfl_xor(p1, off);
      }
      const int ms0 = mb[g * kT + s];
      const int ms1 = mb[g * kT + s + 1];
      double sc0, sc1;
      if (mqg) {
        sc0 = ms0 ? ((double)p0 + Qbk) * 0.0625 : Cm;
        sc1 = ms1 ? ((double)p1 + Qbk) * 0.0625 : Cm;
      } else {
        sc0 = ms0 ? kNeg * ((double)p0 + sbk) * 0.0625 : Cbb;
        sc1 = ms1 ? kNeg * ((double)p1 + sbk) * 0.0625 : Cbb;
      }
      double mnew = m;
      if (sc0 > mnew) mnew = sc0;
      if (sc1 > mnew) mnew = sc1;
      const float al = expf((float)(m - mnew));
      const float e0 = expf((float)(sc0 - mnew));
      const float e1 = expf((float)(sc1 - mnew));
      m = mnew;
      l = l * al + e0 + e1;
      y.x = y.x * al + e0 * a0.x + e1 * a1.x;
      y.y = y.y * al + e0 * a0.y + e1 * a1.y;
      y.z = y.z * al + e0 * a0.z + e1 * a1.z;
      y.w = y.w * al + e0 * a0.w + e1 * a1.w;
    }
    const float inv = 1.0f / l;
    y.x *= inv; y.y *= inv; y.z *= inv; y.w *= inv;
    ((float4*)(&yb[g][0]))[lane] = y;
  }
  __syncthreads();

  // ---- D: out_j[e] = Wv[e,:] . y_j + bv[e] ----
  {
    const int e = t;
    float acc[kG] = {0.f, 0.f, 0.f, 0.f};
    const float4* wr = (const float4*)(Wv + (size_t)e * kD);
    for (int i = 0; i < kD / 4; ++i) {
      const float4 w = wr[i];
#pragma unroll
      for (int j = 0; j < kG; ++j) {
        const float4 yv = ((const float4*)(&yb[j][0]))[i];
        acc[j] += w.x * yv.x + w.y * yv.y + w.z * yv.z + w.w * yv.w;
      }
    }
    const float be = bv[e];
#pragma unroll
    for (int j = 0; j < kG; ++j)
      out[(size_t)(b0 + j) * kD + e] = acc[j] + be;
  }
}

extern "C" void kernel_launch(void* const* d_in, const int* in_sizes, int n_in,
                              void* d_out, int out_size, void* d_ws,
                              size_t ws_size, hipStream_t stream) {
  const float* x = (const float*)d_in[0];
  const int* mask = (const int*)d_in[1];
  const float* td = (const float*)d_in[2];
  const float* Wq = (const float*)d_in[3];
  const float* bq = (const float*)d_in[4];
  const float* Wk = (const float*)d_in[5];
  const float* bk = (const float*)d_in[6];
  const float* Wv = (const float*)d_in[7];
  const float* bv = (const float*)d_in[8];
  float* out = (float*)d_out;
  (void)d_ws; (void)ws_size; (void)in_sizes; (void)n_in; (void)out_size;

  hipLaunchKernelGGL(attn_fused, dim3(kB / kG), dim3(kThr), 0, stream, x, mask,
                     td, Wq, bq, Wk, bk, Wv, bv, out);
}